// Round 5
// baseline (275.032 us; speedup 1.0000x reference)
//
#include <hip/hip_runtime.h>

// GymNetwork: routed MLP, B=262144, D=128 -> F=80 -> 80 -> 80 -> A=18, G=8 (idx sorted).
// f32 I/O, bf16 MFMA compute (threshold 6e-2 = 8*bf16_eps*max|ref|).
//
// R4 was latency-bound by the per-block serial chain: stage -> barrier -> L1 -> barrier ->
// L2 -> L3 -> L4, two full vmcnt(0) barrier drains per small block, waves in lockstep.
// R5: ZERO barriers. Each wave owns 16 rows end-to-end:
//   - state loaded straight into A-fragment registers (coalesced dwordx4 pairs + f32->bf16)
//   - h1/h2/h3 in a wave-private LDS buffer (3.3 KB/wave); each layer reads its A-frags to
//     registers before overwriting the buffer (wave-private -> program order suffices)
//   - routing masks in registers (idx sorted -> per-wave [g_lo, g_hi])
// Weights pre-converted/padded to bf16 in d_ws by a tiny prologue kernel.

#define B_TOT   262144
#define DDIM    128
#define NGAMES  8
#define FDIM    80
#define ADIM    18
#define ROWS_W  16     // rows per wave
#define MT      64     // rows per block (4 waves)
#define SH      104    // LDS stride (shorts) for h rows
#define KP      96     // padded K for feature layers

// bf16 weight workspace layout (shorts)
#define W1O     0                       // [G][80][128]
#define W2O     81920                   // [80][96]  (k pads zeroed)
#define W3O     89600                   // [80][96]
#define W4O     97280                   // [G][32][96] (n,k pads zeroed)
#define WTOT    121856                  // shorts = 243712 bytes

typedef __attribute__((ext_vector_type(8))) short short8;
typedef __attribute__((ext_vector_type(4))) float floatx4;

static __device__ __forceinline__ unsigned short f2bf(float f) {
  union { float f; unsigned u; } v; v.f = f;
  unsigned r = v.u + 0x7fffu + ((v.u >> 16) & 1u);   // RNE
  return (unsigned short)(r >> 16);
}

// ---- prologue: f32 weights -> bf16 (padded) in ws ----
__global__ void convert_weights(const float* __restrict__ W1, const float* __restrict__ W2,
                                const float* __restrict__ W3, const float* __restrict__ W4,
                                unsigned short* __restrict__ ws) {
  int t = blockIdx.x * 256 + threadIdx.x;
  if (t < W2O) {                                   // W1: straight copy-convert
    ws[t] = f2bf(W1[t]);
  } else if (t < W3O) {                            // W2: 80x80 -> 80x96
    int i = t - W2O, n = i / KP, k = i - n * KP;
    ws[t] = (k < FDIM) ? f2bf(W2[n * FDIM + k]) : (unsigned short)0;
  } else if (t < W4O) {                            // W3
    int i = t - W3O, n = i / KP, k = i - n * KP;
    ws[t] = (k < FDIM) ? f2bf(W3[n * FDIM + k]) : (unsigned short)0;
  } else if (t < WTOT) {                           // W4: Gx18x80 -> Gx32x96
    int i = t - W4O, g = i / (32 * KP), r = i - g * (32 * KP);
    int n = r / KP, k = r - n * KP;
    ws[t] = (n < ADIM && k < FDIM) ? f2bf(W4[(g * ADIM + n) * FDIM + k]) : (unsigned short)0;
  }
}

// Load 8 consecutive f32 and pack to a bf16 short8 A-fragment.
static __device__ __forceinline__ short8 ld_frag8_f32(const float* p) {
  floatx4 a = *(const floatx4*)p;
  floatx4 b = *(const floatx4*)(p + 4);
  short8 r;
  r[0] = (short)f2bf(a[0]); r[1] = (short)f2bf(a[1]);
  r[2] = (short)f2bf(a[2]); r[3] = (short)f2bf(a[3]);
  r[4] = (short)f2bf(b[0]); r[5] = (short)f2bf(b[1]);
  r[6] = (short)f2bf(b[2]); r[7] = (short)f2bf(b[3]);
  return r;
}

// Shared 80x80 layer on a wave-private h buffer, in place:
// reads A-frags (3 x b128) to registers, MFMAs, then overwrites hbuf with relu(out).
static __device__ __forceinline__ void mlp_layer_inplace(
    unsigned short* hbuf,              // wave-private [16][SH]
    const unsigned short* __restrict__ Wbf,   // [80][KP] bf16, k pads zero
    const float* __restrict__ bias,
    int l16, int quad)
{
  short8 a[3];
#pragma unroll
  for (int ks = 0; ks < 3; ++ks)
    a[ks] = *(const short8*)(hbuf + l16 * SH + ks * 32 + quad * 8);

  floatx4 acc[5];
#pragma unroll
  for (int ct = 0; ct < 5; ++ct) acc[ct] = (floatx4){0.f, 0.f, 0.f, 0.f};
#pragma unroll
  for (int ks = 0; ks < 3; ++ks) {
    int k0 = ks * 32 + quad * 8;
#pragma unroll
    for (int ct = 0; ct < 5; ++ct) {
      short8 bf = *(const short8*)(Wbf + (ct * 16 + l16) * KP + k0);
      acc[ct] = __builtin_amdgcn_mfma_f32_16x16x32_bf16(a[ks], bf, acc[ct], 0, 0, 0);
    }
  }
#pragma unroll
  for (int ct = 0; ct < 5; ++ct) {
    int col = ct * 16 + l16;
    float bv = bias[col];
#pragma unroll
    for (int r = 0; r < 4; ++r) {
      int row = quad * 4 + r;          // C/D: col=lane&15, row=quad*4+reg
      hbuf[row * SH + col] = f2bf(fmaxf(acc[ct][r] + bv, 0.f));
    }
  }
}

__global__ __launch_bounds__(256, 5) void gym_fused(
    const float* __restrict__ state, const int* __restrict__ idx,
    const unsigned short* __restrict__ wbf,
    const float* __restrict__ b1, const float* __restrict__ b2,
    const float* __restrict__ b3, const float* __restrict__ b4,
    float* __restrict__ out)
{
  __shared__ __align__(16) unsigned short s_h[4][ROWS_W * SH];  // 13312 B, wave-private slices

  const int tid  = threadIdx.x;
  const int lane = tid & 63;
  const int wv   = tid >> 6;
  const int l16  = lane & 15;
  const int quad = lane >> 4;
  unsigned short* hbuf = s_h[wv];
  const size_t row0 = (size_t)blockIdx.x * MT + wv * ROWS_W;   // this wave's 16 rows
  const short8 zero8 = {0, 0, 0, 0, 0, 0, 0, 0};

  // ---- per-lane routing registers (idx sorted) ----
  int idxr[4];
#pragma unroll
  for (int r = 0; r < 4; ++r) idxr[r] = idx[row0 + quad * 4 + r];
  const int g_lo = idx[row0];
  const int g_hi = idx[row0 + ROWS_W - 1];

  // ---- zero h pad cols 80..95 (uninitialized LDS; NaN*0=NaN through MFMA) ----
  if (lane < 32) {
    int r = lane >> 1, cc = lane & 1;
    *(short8*)(hbuf + r * SH + 80 + cc * 8) = zero8;
  }

  // ---- load state A-fragments straight from global (f32 -> bf16 in regs) ----
  short8 afrag[4];
  {
    const float* sp = state + (row0 + l16) * DDIM + quad * 8;
#pragma unroll
    for (int ks = 0; ks < 4; ++ks)
      afrag[ks] = ld_frag8_f32(sp + ks * 32);
  }

  // ---- layer 1 (routed): h1 = relu(state @ W1[g]^T + b1[g]) ----
  for (int g = g_lo; g <= g_hi; ++g) {
    floatx4 acc[5];
#pragma unroll
    for (int ct = 0; ct < 5; ++ct) acc[ct] = (floatx4){0.f, 0.f, 0.f, 0.f};
    const unsigned short* w1g = wbf + W1O + g * (FDIM * DDIM);
#pragma unroll
    for (int ks = 0; ks < 4; ++ks) {
      int k0 = ks * 32 + quad * 8;
#pragma unroll
      for (int ct = 0; ct < 5; ++ct) {
        short8 bf = *(const short8*)(w1g + (ct * 16 + l16) * DDIM + k0);
        acc[ct] = __builtin_amdgcn_mfma_f32_16x16x32_bf16(afrag[ks], bf, acc[ct], 0, 0, 0);
      }
    }
#pragma unroll
    for (int ct = 0; ct < 5; ++ct) {
      int col = ct * 16 + l16;
      float bv = b1[g * FDIM + col];
#pragma unroll
      for (int r = 0; r < 4; ++r) {
        if (idxr[r] == g) {
          int row = quad * 4 + r;
          hbuf[row * SH + col] = f2bf(fmaxf(acc[ct][r] + bv, 0.f));
        }
      }
    }
  }

  // ---- layers 2,3 (shared), in place on the wave-private buffer ----
  mlp_layer_inplace(hbuf, wbf + W2O, b2, l16, quad);
  mlp_layer_inplace(hbuf, wbf + W3O, b3, l16, quad);

  // ---- layer 4 (routed heads): q = h3 @ W4[g]^T + b4[g], f32 out ----
  short8 a3[3];
#pragma unroll
  for (int ks = 0; ks < 3; ++ks)
    a3[ks] = *(const short8*)(hbuf + l16 * SH + ks * 32 + quad * 8);

  for (int g = g_lo; g <= g_hi; ++g) {
    floatx4 acc[2];
#pragma unroll
    for (int ct = 0; ct < 2; ++ct) acc[ct] = (floatx4){0.f, 0.f, 0.f, 0.f};
    const unsigned short* w4g = wbf + W4O + g * (32 * KP);
#pragma unroll
    for (int ks = 0; ks < 3; ++ks) {
      int k0 = ks * 32 + quad * 8;
#pragma unroll
      for (int ct = 0; ct < 2; ++ct) {
        short8 bf = *(const short8*)(w4g + (ct * 16 + l16) * KP + k0);  // n,k pads zero
        acc[ct] = __builtin_amdgcn_mfma_f32_16x16x32_bf16(a3[ks], bf, acc[ct], 0, 0, 0);
      }
    }
#pragma unroll
    for (int ct = 0; ct < 2; ++ct) {
      int col = ct * 16 + l16;
      if (col < ADIM) {
        float bv = b4[g * ADIM + col];
#pragma unroll
        for (int r = 0; r < 4; ++r) {
          if (idxr[r] == g)
            out[(row0 + quad * 4 + r) * ADIM + col] = acc[ct][r] + bv;
        }
      }
    }
  }
}

extern "C" void kernel_launch(void* const* d_in, const int* in_sizes, int n_in,
                              void* d_out, int out_size, void* d_ws, size_t ws_size,
                              hipStream_t stream) {
  const float* state = (const float*)d_in[0];
  const int*   idx   = (const int*)d_in[1];
  const float* W1    = (const float*)d_in[2];
  const float* b1    = (const float*)d_in[3];
  const float* W2    = (const float*)d_in[4];
  const float* b2    = (const float*)d_in[5];
  const float* W3    = (const float*)d_in[6];
  const float* b3    = (const float*)d_in[7];
  const float* W4    = (const float*)d_in[8];
  const float* b4    = (const float*)d_in[9];
  float*       out   = (float*)d_out;
  unsigned short* wbf = (unsigned short*)d_ws;   // 243712 B used

  convert_weights<<<(WTOT + 255) / 256, 256, 0, stream>>>(W1, W2, W3, W4, wbf);
  gym_fused<<<B_TOT / MT, 256, 0, stream>>>(state, idx, wbf, b1, b2, b3, b4, out);
}

// Round 6
// 231.370 us; speedup vs baseline: 1.1887x; 1.1887x over previous
//
#include <hip/hip_runtime.h>

// GymNetwork: routed MLP, B=262144, D=128 -> F=80 -> 80 -> 80 -> A=18, G=8 (idx sorted).
// f32 I/O, bf16 MFMA compute (threshold 6e-2 = 8*bf16_eps*max|ref|).
//
// R3-R5 invariant ~120us: B-fragment loads were 16-line half-used gathers; L1 line
// throughput + exposed latency dominated (all pipes <15% busy, wave lifetime ~67k cyc).
// R6: (1) prologue pre-SWIZZLES weights into MFMA fragment lane order -- each (layer,ct,ks)
//     fragment is a contiguous 1KB chunk, loaded as ONE coalesced dwordx4 per lane;
//     (2) ROWS_W=32 (two row-halves per wave) -> 2x MFMA per weight load;
//     (3) zero barriers (wave-private h buffers), routing via sorted per-wave [g_lo,g_hi].

#define B_TOT   262144
#define DDIM    128
#define NGAMES  8
#define FDIM    80
#define ADIM    18
#define ROWS_W  32     // rows per wave
#define MT      128    // rows per block (4 waves)
#define SH      104    // LDS stride (shorts) for h rows
#define KP      96     // padded K for feature layers

// swizzled bf16 weight workspace (shorts); 512-short (1KB) chunks, lane-major
#define W1SW    0                       // 160 chunks: ((g*4+ks)*5+ct)
#define W2SW    81920                   // 15 chunks: (ks*5+ct), k pads zeroed
#define W3SW    89600                   // 15 chunks
#define W4SW    97280                   // 48 chunks: ((g*3+ks)*2+ct), n/k pads zeroed
#define WTOT    121856                  // shorts = 243712 bytes

typedef __attribute__((ext_vector_type(8))) short short8;
typedef __attribute__((ext_vector_type(4))) float floatx4;

static __device__ __forceinline__ unsigned short f2bf(float f) {
  union { float f; unsigned u; } v; v.f = f;
  unsigned r = v.u + 0x7fffu + ((v.u >> 16) & 1u);   // RNE
  return (unsigned short)(r >> 16);
}

// ---- prologue: f32 weights -> bf16, swizzled to MFMA B-fragment lane order ----
// chunk layout: ws[chunk*512 + lane*8 + j] = W[n = ct*16 + (lane&15)][k = ks*32 + (lane>>4)*8 + j]
__global__ void convert_weights(const float* __restrict__ W1, const float* __restrict__ W2,
                                const float* __restrict__ W3, const float* __restrict__ W4,
                                unsigned short* __restrict__ ws) {
  int t = blockIdx.x * 256 + threadIdx.x;
  if (t >= WTOT) return;
  int chunk = t >> 9, r = t & 511;
  int lane = r >> 3, j = r & 7;
  int l16 = lane & 15, quad = lane >> 4;
  float val;
  if (chunk < 160) {                              // W1: [G][80][128]
    int g = chunk / 20, rem = chunk % 20, ks = rem / 5, ct = rem % 5;
    int n = ct * 16 + l16, k = ks * 32 + quad * 8 + j;
    val = W1[(g * FDIM + n) * DDIM + k];
  } else if (chunk < 175) {                       // W2: [80][80] -> k padded 96
    int c = chunk - 160, ks = c / 5, ct = c % 5;
    int n = ct * 16 + l16, k = ks * 32 + quad * 8 + j;
    val = (k < FDIM) ? W2[n * FDIM + k] : 0.f;
  } else if (chunk < 190) {                       // W3
    int c = chunk - 175, ks = c / 5, ct = c % 5;
    int n = ct * 16 + l16, k = ks * 32 + quad * 8 + j;
    val = (k < FDIM) ? W3[n * FDIM + k] : 0.f;
  } else {                                        // W4: [G][18][80] -> [G][32][96]
    int c = chunk - 190, g = c / 6, rem = c % 6, ks = rem >> 1, ct = rem & 1;
    int n = ct * 16 + l16, k = ks * 32 + quad * 8 + j;
    val = (n < ADIM && k < FDIM) ? W4[(g * ADIM + n) * FDIM + k] : 0.f;
  }
  ws[t] = f2bf(val);
}

// Load 8 consecutive f32 and pack to a bf16 short8 A-fragment.
static __device__ __forceinline__ short8 ld_frag8_f32(const float* p) {
  floatx4 a = *(const floatx4*)p;
  floatx4 b = *(const floatx4*)(p + 4);
  short8 r;
  r[0] = (short)f2bf(a[0]); r[1] = (short)f2bf(a[1]);
  r[2] = (short)f2bf(a[2]); r[3] = (short)f2bf(a[3]);
  r[4] = (short)f2bf(b[0]); r[5] = (short)f2bf(b[1]);
  r[6] = (short)f2bf(b[2]); r[7] = (short)f2bf(b[3]);
  return r;
}

// Shared 80x80 layer on wave-private hbuf (32 rows), in place.
static __device__ __forceinline__ void mlp_layer_inplace(
    unsigned short* hbuf,                         // [32][SH]
    const unsigned short* __restrict__ wsw,       // 15 swizzled chunks (ks*5+ct)
    const float* __restrict__ bias,
    int lane, int l16, int quad)
{
  short8 a[2][3];
#pragma unroll
  for (int s = 0; s < 2; ++s)
#pragma unroll
    for (int ks = 0; ks < 3; ++ks)
      a[s][ks] = *(const short8*)(hbuf + (s * 16 + l16) * SH + ks * 32 + quad * 8);

  floatx4 acc[2][5];
#pragma unroll
  for (int s = 0; s < 2; ++s)
#pragma unroll
    for (int ct = 0; ct < 5; ++ct) acc[s][ct] = (floatx4){0.f, 0.f, 0.f, 0.f};
#pragma unroll
  for (int ks = 0; ks < 3; ++ks)
#pragma unroll
    for (int ct = 0; ct < 5; ++ct) {
      short8 bf = *(const short8*)(wsw + (ks * 5 + ct) * 512 + lane * 8);
      acc[0][ct] = __builtin_amdgcn_mfma_f32_16x16x32_bf16(a[0][ks], bf, acc[0][ct], 0, 0, 0);
      acc[1][ct] = __builtin_amdgcn_mfma_f32_16x16x32_bf16(a[1][ks], bf, acc[1][ct], 0, 0, 0);
    }
#pragma unroll
  for (int s = 0; s < 2; ++s)
#pragma unroll
    for (int ct = 0; ct < 5; ++ct) {
      int col = ct * 16 + l16;
      float bv = bias[col];
#pragma unroll
      for (int r = 0; r < 4; ++r) {
        int row = s * 16 + quad * 4 + r;          // C/D: col=lane&15, row=quad*4+reg
        hbuf[row * SH + col] = f2bf(fmaxf(acc[s][ct][r] + bv, 0.f));
      }
    }
}

__global__ __launch_bounds__(256, 4) void gym_fused(
    const float* __restrict__ state, const int* __restrict__ idx,
    const unsigned short* __restrict__ wsw,
    const float* __restrict__ b1, const float* __restrict__ b2,
    const float* __restrict__ b3, const float* __restrict__ b4,
    float* __restrict__ out)
{
  __shared__ __align__(16) unsigned short s_h[4][ROWS_W * SH];  // 26624 B, wave-private slices

  const int tid  = threadIdx.x;
  const int lane = tid & 63;
  const int wv   = tid >> 6;
  const int l16  = lane & 15;
  const int quad = lane >> 4;
  unsigned short* hbuf = s_h[wv];
  const size_t row0 = (size_t)blockIdx.x * MT + wv * ROWS_W;   // this wave's 32 rows
  const short8 zero8 = {0, 0, 0, 0, 0, 0, 0, 0};

  // ---- per-lane routing registers (idx sorted) ----
  int idxr[2][4];
#pragma unroll
  for (int s = 0; s < 2; ++s)
#pragma unroll
    for (int r = 0; r < 4; ++r) idxr[s][r] = idx[row0 + s * 16 + quad * 4 + r];
  const int g_lo = idx[row0];
  const int g_hi = idx[row0 + ROWS_W - 1];

  // ---- zero h pad cols 80..95 (uninitialized LDS; NaN*0=NaN through MFMA) ----
  {
    int r = lane >> 1, cc = lane & 1;             // 32 rows x 2 chunks = 64 writes
    *(short8*)(hbuf + r * SH + 80 + cc * 8) = zero8;
  }

  // ---- state A-fragments straight from global (f32 -> bf16 in regs) ----
  short8 afrag[2][4];
#pragma unroll
  for (int s = 0; s < 2; ++s) {
    const float* sp = state + (row0 + s * 16 + l16) * DDIM + quad * 8;
#pragma unroll
    for (int ks = 0; ks < 4; ++ks)
      afrag[s][ks] = ld_frag8_f32(sp + ks * 32);
  }

  // ---- layer 1 (routed): h1 = relu(state @ W1[g]^T + b1[g]) ----
  for (int g = g_lo; g <= g_hi; ++g) {
    floatx4 acc[2][5];
#pragma unroll
    for (int s = 0; s < 2; ++s)
#pragma unroll
      for (int ct = 0; ct < 5; ++ct) acc[s][ct] = (floatx4){0.f, 0.f, 0.f, 0.f};
#pragma unroll
    for (int ks = 0; ks < 4; ++ks)
#pragma unroll
      for (int ct = 0; ct < 5; ++ct) {
        short8 bf = *(const short8*)(wsw + W1SW + (((g * 4 + ks) * 5) + ct) * 512 + lane * 8);
        acc[0][ct] = __builtin_amdgcn_mfma_f32_16x16x32_bf16(afrag[0][ks], bf, acc[0][ct], 0, 0, 0);
        acc[1][ct] = __builtin_amdgcn_mfma_f32_16x16x32_bf16(afrag[1][ks], bf, acc[1][ct], 0, 0, 0);
      }
#pragma unroll
    for (int s = 0; s < 2; ++s)
#pragma unroll
      for (int ct = 0; ct < 5; ++ct) {
        int col = ct * 16 + l16;
        float bv = b1[g * FDIM + col];
#pragma unroll
        for (int r = 0; r < 4; ++r) {
          if (idxr[s][r] == g) {
            int row = s * 16 + quad * 4 + r;
            hbuf[row * SH + col] = f2bf(fmaxf(acc[s][ct][r] + bv, 0.f));
          }
        }
      }
  }

  // ---- layers 2,3 (shared), in place on the wave-private buffer ----
  mlp_layer_inplace(hbuf, wsw + W2SW, b2, lane, l16, quad);
  mlp_layer_inplace(hbuf, wsw + W3SW, b3, lane, l16, quad);

  // ---- layer 4 (routed heads): q = h3 @ W4[g]^T + b4[g], f32 out ----
  short8 a3[2][3];
#pragma unroll
  for (int s = 0; s < 2; ++s)
#pragma unroll
    for (int ks = 0; ks < 3; ++ks)
      a3[s][ks] = *(const short8*)(hbuf + (s * 16 + l16) * SH + ks * 32 + quad * 8);

  for (int g = g_lo; g <= g_hi; ++g) {
    floatx4 acc[2][2];
#pragma unroll
    for (int s = 0; s < 2; ++s)
#pragma unroll
      for (int ct = 0; ct < 2; ++ct) acc[s][ct] = (floatx4){0.f, 0.f, 0.f, 0.f};
#pragma unroll
    for (int ks = 0; ks < 3; ++ks)
#pragma unroll
      for (int ct = 0; ct < 2; ++ct) {
        short8 bf = *(const short8*)(wsw + W4SW + (((g * 3 + ks) * 2) + ct) * 512 + lane * 8);
        acc[0][ct] = __builtin_amdgcn_mfma_f32_16x16x32_bf16(a3[0][ks], bf, acc[0][ct], 0, 0, 0);
        acc[1][ct] = __builtin_amdgcn_mfma_f32_16x16x32_bf16(a3[1][ks], bf, acc[1][ct], 0, 0, 0);
      }
#pragma unroll
    for (int s = 0; s < 2; ++s)
#pragma unroll
      for (int ct = 0; ct < 2; ++ct) {
        int col = ct * 16 + l16;
        if (col < ADIM) {
          float bv = b4[g * ADIM + col];
#pragma unroll
          for (int r = 0; r < 4; ++r) {
            if (idxr[s][r] == g)
              out[(row0 + s * 16 + quad * 4 + r) * ADIM + col] = acc[s][ct][r] + bv;
          }
        }
      }
  }
}

extern "C" void kernel_launch(void* const* d_in, const int* in_sizes, int n_in,
                              void* d_out, int out_size, void* d_ws, size_t ws_size,
                              hipStream_t stream) {
  const float* state = (const float*)d_in[0];
  const int*   idx   = (const int*)d_in[1];
  const float* W1    = (const float*)d_in[2];
  const float* b1    = (const float*)d_in[3];
  const float* W2    = (const float*)d_in[4];
  const float* b2    = (const float*)d_in[5];
  const float* W3    = (const float*)d_in[6];
  const float* b3    = (const float*)d_in[7];
  const float* W4    = (const float*)d_in[8];
  const float* b4    = (const float*)d_in[9];
  float*       out   = (float*)d_out;
  unsigned short* wsw = (unsigned short*)d_ws;   // 243712 B used

  convert_weights<<<(WTOT + 255) / 256, 256, 0, stream>>>(W1, W2, W3, W4, wsw);
  gym_fused<<<B_TOT / MT, 256, 0, stream>>>(state, idx, wsw, b1, b2, b3, b4, out);
}